// Round 1
// baseline (3268.895 us; speedup 1.0000x reference)
//
#include <hip/hip_runtime.h>
#include <hip/hip_fp16.h>
#include <cstdio>

typedef unsigned short u16;
typedef __attribute__((ext_vector_type(8))) _Float16 f16x8;
typedef __attribute__((ext_vector_type(4))) float fv4;

#define TT 512
#define BB 256
#define MROWS (TT * BB)   // 131072

__device__ __forceinline__ float us2f(u16 u) {
    union { u16 u; _Float16 h; } c; c.u = u; return (float)c.h;
}
__device__ __forceinline__ u16 f2us(float f) {
    union { u16 u; _Float16 h; } c; c.h = (_Float16)f; return c.u;
}

// async global->LDS, 16B per lane. LDS dest must be wave-uniform base + lane*16.
__device__ __forceinline__ void gl_lds16(const u16* g, u16* l) {
    __builtin_amdgcn_global_load_lds(
        (const __attribute__((address_space(1))) void*)g,
        (__attribute__((address_space(3))) void*)l, 16, 0, 0);
}

// ---------------- fp32 -> fp16 convert (n % 8 == 0) ----------------
__global__ void cvt_f32_f16(const float* __restrict__ s, u16* __restrict__ d, int n) {
    long stride = (long)gridDim.x * blockDim.x * 8;
    for (long i = ((long)blockIdx.x * blockDim.x + threadIdx.x) * 8; i < n; i += stride) {
        f16x8 o;
#pragma unroll
        for (int j = 0; j < 8; ++j) o[j] = (_Float16)s[i + j];
        *(f16x8*)(d + i) = o;
    }
}

// ---------------- pack W_hh [768,256] into MFMA B-frag order ----------------
// Wp[((jt*8 + kt)*64 + lane)*8 + i] = Whh[jt*16 + (lane&15)][kt*32 + (lane>>4)*8 + i]
__global__ void pack_whh(const float* __restrict__ W, u16* __restrict__ Wp) {
    int t = blockIdx.x * blockDim.x + threadIdx.x;   // 0..24575
    int l = t & 63;
    int kt = (t >> 6) & 7;
    int jt = t >> 9;                                  // 0..47
    int j = jt * 16 + (l & 15);
    int k = kt * 32 + (l >> 4) * 8;
    f16x8 o;
#pragma unroll
    for (int i = 0; i < 8; ++i) o[i] = (_Float16)W[j * 256 + k + i];
    *(f16x8*)(Wp + (size_t)t * 8) = o;
}

// ---------------- pack W2b [18,512] zero-padded to [32,512] in B-frag order --
// W2p[((nt*16 + kt)*64 + lane)*8 + i] = W[nt*16+(lane&15)][kt*32+(lane>>4)*8+i]
__global__ void pack_w2b(const float* __restrict__ W, u16* __restrict__ Wp) {
    int t = blockIdx.x * blockDim.x + threadIdx.x;   // 0..2047
    int l = t & 63;
    int kt = (t >> 6) & 15;
    int nt = t >> 10;                                 // 0..1
    int n = nt * 16 + (l & 15);
    int k = kt * 32 + (l >> 4) * 8;
    f16x8 o;
#pragma unroll
    for (int i = 0; i < 8; ++i)
        o[i] = (n < 18) ? (_Float16)W[n * 512 + k + i] : (_Float16)0.f;
    *(f16x8*)(Wp + (size_t)t * 8) = o;
}

// ---------------- generic fp16 GEMM: C[m,n] = act(sum_k A[m,k]*B[n,k] + bias[n])
// A [M,K] row-major f16, B = weights [N,K] row-major f16 (torch Linear layout).
// 128x128 tile, BK=32, 256 threads, m97-style global_load_lds staging.
__global__ __launch_bounds__(256) void gemm_bt(
    const u16* __restrict__ A, const u16* __restrict__ B,
    const float* __restrict__ bias, u16* __restrict__ C,
    int N, int K, int act)
{
    __shared__ u16 Ash[4096] __attribute__((aligned(16)));
    __shared__ u16 Bsh[4096] __attribute__((aligned(16)));
    const int tid = threadIdx.x;
    const int l = tid & 63, w = tid >> 6;
    const long m0 = (long)blockIdx.y * 128;
    const int n0 = blockIdx.x * 128;
    const int r = tid >> 2, c8 = (tid & 3) * 8;
    const u16* gA0 = A + (m0 + r) * K + c8;
    const u16* gA1 = A + (m0 + 64 + r) * K + c8;
    const u16* gB0 = B + (long)(n0 + r) * K + c8;
    const u16* gB1 = B + (long)(n0 + 64 + r) * K + c8;
    const int mb = (w >> 1) * 64, nb = (w & 1) * 64;
    const int mrow = l & 15, colq = (l >> 4) * 8;
    fv4 acc[4][4] = {};
    for (int k0 = 0; k0 < K; k0 += 32) {
        gl_lds16(gA0 + k0, &Ash[tid * 8]);
        gl_lds16(gA1 + k0, &Ash[2048 + tid * 8]);
        gl_lds16(gB0 + k0, &Bsh[tid * 8]);
        gl_lds16(gB1 + k0, &Bsh[2048 + tid * 8]);
        __syncthreads();
        f16x8 af[4], bf[4];
#pragma unroll
        for (int i = 0; i < 4; ++i)
            af[i] = *(const f16x8*)&Ash[(mb + i * 16 + mrow) * 32 + colq];
#pragma unroll
        for (int i = 0; i < 4; ++i)
            bf[i] = *(const f16x8*)&Bsh[(nb + i * 16 + mrow) * 32 + colq];
#pragma unroll
        for (int mt = 0; mt < 4; ++mt)
#pragma unroll
            for (int nt = 0; nt < 4; ++nt)
                acc[mt][nt] = __builtin_amdgcn_mfma_f32_16x16x32_f16(
                    af[mt], bf[nt], acc[mt][nt], 0, 0, 0);
        __syncthreads();
    }
    float bv[4];
#pragma unroll
    for (int nt = 0; nt < 4; ++nt) bv[nt] = bias[n0 + nb + nt * 16 + mrow];
    const int rq = (l >> 4) * 4;
#pragma unroll
    for (int mt = 0; mt < 4; ++mt)
#pragma unroll
        for (int nt = 0; nt < 4; ++nt)
#pragma unroll
            for (int i = 0; i < 4; ++i) {
                float v = acc[mt][nt][i] + bv[nt];
                if (act) v = fmaxf(v, 0.f);
                C[(m0 + mb + mt * 16 + rq + i) * (long)N + (n0 + nb + nt * 16 + mrow)] = f2us(v);
            }
}

// ---------------- sequential GRU: 16 blocks x 512 threads (8 waves) ----------
// Block g owns batch rows [16g, 16g+16). Wave w owns k-slices {2w, 2w+1}
// i.e. j-tiles jt = gate*16 + 2w + s for gate in {r,z,n}, s in {0,1}.
// h kept in LDS in A-frag layout: h_sh[(kt*64 + lane)*8 + i] = h[lane&15][kt*32+(lane>>4)*8+i]
__global__ __launch_bounds__(512) void gru_seq(
    const u16* __restrict__ Wp, const u16* __restrict__ GI,
    const float* __restrict__ b_hh, u16* __restrict__ Hout)
{
    __shared__ u16 h_sh[4096] __attribute__((aligned(16)));
    const int tid = threadIdx.x;
    const int l = tid & 63, w = tid >> 6;
    const int bg = blockIdx.x * 16;
    const int col = l & 15, quad = l >> 4;

    for (int i = tid; i < 4096; i += 512) h_sh[i] = 0;
    __syncthreads();

    // per-lane b_hh biases; u = g*2 + s
    float hb[6];
    const u16* wpb[6];
#pragma unroll
    for (int g = 0; g < 3; ++g)
#pragma unroll
        for (int s = 0; s < 2; ++s) {
            hb[g * 2 + s] = b_hh[g * 256 + 32 * w + s * 16 + col];
            int jt = g * 16 + 2 * w + s;
            wpb[g * 2 + s] = Wp + (size_t)jt * 4096 + l * 8;
        }
    long base[4];
#pragma unroll
    for (int i = 0; i < 4; ++i)
        base[i] = (long)(bg + quad * 4 + i) * 768 + 32 * w + col;

    float hold[2][4] = {};

    for (int t = 0; t < TT; ++t) {
        // prefetch gi (needed only in epilogue)
        float gi[6][4];
        const u16* gp = GI + (size_t)t * (BB * 768);
#pragma unroll
        for (int i = 0; i < 4; ++i) {
            const u16* p = gp + base[i];
#pragma unroll
            for (int g = 0; g < 3; ++g)
#pragma unroll
                for (int s = 0; s < 2; ++s)
                    gi[g * 2 + s][i] = us2f(p[g * 256 + s * 16]);
        }
        // K-loop: stream W_hh frags from L2, double-buffered
        fv4 acc[6] = {};
        f16x8 bcur[6], bnxt[6];
#pragma unroll
        for (int u = 0; u < 6; ++u) bcur[u] = *(const f16x8*)(wpb[u]);
#pragma unroll
        for (int kt = 0; kt < 8; ++kt) {
            if (kt < 7) {
#pragma unroll
                for (int u = 0; u < 6; ++u)
                    bnxt[u] = *(const f16x8*)(wpb[u] + (kt + 1) * 512);
            }
            f16x8 a = *(const f16x8*)&h_sh[(kt * 64 + l) * 8];
#pragma unroll
            for (int u = 0; u < 6; ++u)
                acc[u] = __builtin_amdgcn_mfma_f32_16x16x32_f16(a, bcur[u], acc[u], 0, 0, 0);
#pragma unroll
            for (int u = 0; u < 6; ++u) bcur[u] = bnxt[u];
        }
        __syncthreads();   // all h_sh reads done before overwrite
        // epilogue: gates + h update. acc row b = quad*4+i, col k = 32w + s*16 + col
#pragma unroll
        for (int s = 0; s < 2; ++s) {
            const int q2 = s * 2 + (col >> 3);
#pragma unroll
            for (int i = 0; i < 4; ++i) {
                float h_r = acc[0 + s][i] + hb[0 + s];
                float h_z = acc[2 + s][i] + hb[2 + s];
                float h_n = acc[4 + s][i] + hb[4 + s];
                float rg = 1.f / (1.f + __expf(-(gi[0 + s][i] + h_r)));
                float zg = 1.f / (1.f + __expf(-(gi[2 + s][i] + h_z)));
                float pre = gi[4 + s][i] + rg * h_n;
                float ea = __expf(-2.f * fabsf(pre));
                float th = (1.f - ea) / (1.f + ea);
                float ng = (pre >= 0.f) ? th : -th;
                float hn = (1.f - zg) * ng + zg * hold[s][i];
                hold[s][i] = hn;
                u16 hu = f2us(hn);
                // write back to frag layout: kt=w, lane' = q2*16 + b, i' = col&7
                h_sh[(w * 64 + q2 * 16 + quad * 4 + i) * 8 + (col & 7)] = hu;
                Hout[(size_t)(t * BB + bg + quad * 4 + i) * 256 + 32 * w + s * 16 + col] = hu;
            }
        }
        __syncthreads();
    }
}

// ---------------- head: out[m, 0..17] = Q1[m,:512] @ W2b^T + b2b (fp32 out) ---
__global__ __launch_bounds__(256) void head_gemm(
    const u16* __restrict__ Q1, const u16* __restrict__ W2p,
    const float* __restrict__ b2, float* __restrict__ out)
{
    __shared__ u16 Ash[4096] __attribute__((aligned(16)));
    __shared__ u16 Bsh[16384] __attribute__((aligned(16)));
    const int tid = threadIdx.x;
    const int l = tid & 63, w = tid >> 6;
    const long m0 = (long)blockIdx.x * 128;
    const int col = l & 15, quad = l >> 4, colq = quad * 8;
    for (int i = tid * 8; i < 16384; i += 2048)
        *(f16x8*)&Bsh[i] = *(const f16x8*)&W2p[i];
    const int r = tid >> 2, c8 = (tid & 3) * 8;
    const u16* gA0 = Q1 + (m0 + r) * 512 + c8;
    const u16* gA1 = Q1 + (m0 + 64 + r) * 512 + c8;
    fv4 acc[2][2] = {};
    for (int k0 = 0; k0 < 512; k0 += 32) {
        gl_lds16(gA0 + k0, &Ash[tid * 8]);
        gl_lds16(gA1 + k0, &Ash[2048 + tid * 8]);
        __syncthreads();
        const int kt = k0 >> 5;
        f16x8 af[2], bf[2];
#pragma unroll
        for (int mt = 0; mt < 2; ++mt)
            af[mt] = *(const f16x8*)&Ash[(w * 32 + mt * 16 + col) * 32 + colq];
#pragma unroll
        for (int nt = 0; nt < 2; ++nt)
            bf[nt] = *(const f16x8*)&Bsh[((nt * 16 + kt) * 64 + l) * 8];
#pragma unroll
        for (int mt = 0; mt < 2; ++mt)
#pragma unroll
            for (int nt = 0; nt < 2; ++nt)
                acc[mt][nt] = __builtin_amdgcn_mfma_f32_16x16x32_f16(
                    af[mt], bf[nt], acc[mt][nt], 0, 0, 0);
        __syncthreads();
    }
    const int rq = quad * 4;
#pragma unroll
    for (int nt = 0; nt < 2; ++nt) {
        int c = nt * 16 + col;
        if (c < 18) {
            float bias = b2[c];
#pragma unroll
            for (int mt = 0; mt < 2; ++mt)
#pragma unroll
                for (int i = 0; i < 4; ++i)
                    out[(m0 + w * 32 + mt * 16 + rq + i) * 18 + c] = acc[mt][nt][i] + bias;
        }
    }
}

extern "C" void kernel_launch(void* const* d_in, const int* in_sizes, int n_in,
                              void* d_out, int out_size, void* d_ws, size_t ws_size,
                              hipStream_t stream) {
    const float* x   = (const float*)d_in[0];
    const float* W1a = (const float*)d_in[1];
    const float* b1a = (const float*)d_in[2];
    const float* W1b = (const float*)d_in[3];
    const float* b1b = (const float*)d_in[4];
    const float* Wih = (const float*)d_in[5];
    const float* bih = (const float*)d_in[6];
    const float* Whh = (const float*)d_in[7];
    const float* bhh = (const float*)d_in[8];
    const float* W2a = (const float*)d_in[9];
    const float* b2a = (const float*)d_in[10];
    const float* W2b = (const float*)d_in[11];
    const float* b2b = (const float*)d_in[12];

    char* ws = (char*)d_ws;
    // region R: 201326592 B serves A1 [131072,512]f16, then GI [131072,768]f16, then Q1
    u16* R    = (u16*)ws;
    u16* A2b  = (u16*)(ws + 201326592);   //  67108864 B
    u16* XH   = (u16*)(ws + 268435456);   //  67108864 B (x fp16, later Hout)
    u16* W1ah = (u16*)(ws + 335544320);   //    262144 B
    u16* W1bh = (u16*)(ws + 335806464);   //    262144 B
    u16* Wihh = (u16*)(ws + 336068608);   //    393216 B
    u16* W2ah = (u16*)(ws + 336461824);   //    262144 B
    u16* Wpk  = (u16*)(ws + 336723968);   //    393216 B
    u16* W2p  = (u16*)(ws + 337117184);   //     32768 B
    if (ws_size < 337149952) {
        fprintf(stderr, "kernel_launch: ws too small (%zu < 337149952)\n", ws_size);
    }

    cvt_f32_f16<<<dim3(2048), dim3(256), 0, stream>>>(x, XH, 33554432);
    cvt_f32_f16<<<dim3(64), dim3(256), 0, stream>>>(W1a, W1ah, 131072);
    cvt_f32_f16<<<dim3(64), dim3(256), 0, stream>>>(W1b, W1bh, 131072);
    cvt_f32_f16<<<dim3(96), dim3(256), 0, stream>>>(Wih, Wihh, 196608);
    cvt_f32_f16<<<dim3(64), dim3(256), 0, stream>>>(W2a, W2ah, 131072);
    pack_whh<<<dim3(96), dim3(256), 0, stream>>>(Whh, Wpk);
    pack_w2b<<<dim3(8), dim3(256), 0, stream>>>(W2b, W2p);

    // Phase A: time-parallel MLP + input-side GRU gates
    gemm_bt<<<dim3(4, 1024), dim3(256), 0, stream>>>(XH, W1ah, b1a, R,   512, 256, 1);
    gemm_bt<<<dim3(2, 1024), dim3(256), 0, stream>>>(R,  W1bh, b1b, A2b, 256, 512, 1);
    gemm_bt<<<dim3(6, 1024), dim3(256), 0, stream>>>(A2b, Wihh, bih, R,  768, 256, 0);
    // Phase R: sequential GRU (writes H into XH region; x fp16 is dead)
    gru_seq<<<dim3(16), dim3(512), 0, stream>>>(Wpk, R, bhh, XH);
    // Phase B: head
    gemm_bt<<<dim3(4, 1024), dim3(256), 0, stream>>>(XH, W2ah, b2a, R, 512, 256, 1);
    head_gemm<<<dim3(1024), dim3(256), 0, stream>>>(R, W2p, b2b, (float*)d_out);
}

// Round 2
// 1991.842 us; speedup vs baseline: 1.6411x; 1.6411x over previous
//
#include <hip/hip_runtime.h>
#include <hip/hip_fp16.h>
#include <cstdio>

typedef unsigned short u16;
typedef __attribute__((ext_vector_type(8))) _Float16 f16x8;
typedef __attribute__((ext_vector_type(4))) float fv4;

#define TT 512
#define BB 256

__device__ __forceinline__ float us2f(u16 u) {
    union { u16 u; _Float16 h; } c; c.u = u; return (float)c.h;
}
__device__ __forceinline__ u16 f2us(float f) {
    union { u16 u; _Float16 h; } c; c.h = (_Float16)f; return c.u;
}

// async global->LDS, 16B per lane. LDS dest must be wave-uniform base + lane*16.
__device__ __forceinline__ void gl_lds16(const u16* g, u16* l) {
    __builtin_amdgcn_global_load_lds(
        (const __attribute__((address_space(1))) void*)g,
        (__attribute__((address_space(3))) void*)l, 16, 0, 0);
}

// ---------------- fp32 -> fp16 convert (n % 8 == 0) ----------------
__global__ void cvt_f32_f16(const float* __restrict__ s, u16* __restrict__ d, int n) {
    long stride = (long)gridDim.x * blockDim.x * 8;
    for (long i = ((long)blockIdx.x * blockDim.x + threadIdx.x) * 8; i < n; i += stride) {
        f16x8 o;
#pragma unroll
        for (int j = 0; j < 8; ++j) o[j] = (_Float16)s[i + j];
        *(f16x8*)(d + i) = o;
    }
}

// ---------------- bias fold: bsum = b_ih + (j<512 ? b_hh : 0) ----------------
// (n-gate b_hh cannot fold: it sits inside r*(i_n-part); r/z parts can)
__global__ void bias_fold(const float* __restrict__ bih, const float* __restrict__ bhh,
                          float* __restrict__ bsum) {
    int i = blockIdx.x * blockDim.x + threadIdx.x;
    if (i < 768) bsum[i] = bih[i] + (i < 512 ? bhh[i] : 0.f);
}

// ---------------- pack W_hh [768,256] into MFMA B-frag order ----------------
// Wp[((jt*8 + kt)*64 + lane)*8 + i] = Whh[jt*16 + (lane&15)][kt*32 + (lane>>4)*8 + i]
__global__ void pack_whh(const float* __restrict__ W, u16* __restrict__ Wp) {
    int t = blockIdx.x * blockDim.x + threadIdx.x;   // 0..24575
    int l = t & 63;
    int kt = (t >> 6) & 7;
    int jt = t >> 9;                                  // 0..47
    int j = jt * 16 + (l & 15);
    int k = kt * 32 + (l >> 4) * 8;
    f16x8 o;
#pragma unroll
    for (int i = 0; i < 8; ++i) o[i] = (_Float16)W[j * 256 + k + i];
    *(f16x8*)(Wp + (size_t)t * 8) = o;
}

// ---------------- pack W2b [18,512] zero-padded to [32,512] in B-frag order --
__global__ void pack_w2b(const float* __restrict__ W, u16* __restrict__ Wp) {
    int t = blockIdx.x * blockDim.x + threadIdx.x;   // 0..2047
    int l = t & 63;
    int kt = (t >> 6) & 15;
    int nt = t >> 10;                                 // 0..1
    int n = nt * 16 + (l & 15);
    int k = kt * 32 + (l >> 4) * 8;
    f16x8 o;
#pragma unroll
    for (int i = 0; i < 8; ++i)
        o[i] = (n < 18) ? (_Float16)W[n * 512 + k + i] : (_Float16)0.f;
    *(f16x8*)(Wp + (size_t)t * 8) = o;
}

// ---------------- generic fp16 GEMM: C[m,n] = act(sum_k A[m,k]*B[n,k] + bias[n])
__global__ __launch_bounds__(256) void gemm_bt(
    const u16* __restrict__ A, const u16* __restrict__ B,
    const float* __restrict__ bias, u16* __restrict__ C,
    int N, int K, int act)
{
    __shared__ u16 Ash[4096] __attribute__((aligned(16)));
    __shared__ u16 Bsh[4096] __attribute__((aligned(16)));
    const int tid = threadIdx.x;
    const int l = tid & 63, w = tid >> 6;
    const long m0 = (long)blockIdx.y * 128;
    const int n0 = blockIdx.x * 128;
    const int r = tid >> 2, c8 = (tid & 3) * 8;
    const u16* gA0 = A + (m0 + r) * K + c8;
    const u16* gA1 = A + (m0 + 64 + r) * K + c8;
    const u16* gB0 = B + (long)(n0 + r) * K + c8;
    const u16* gB1 = B + (long)(n0 + 64 + r) * K + c8;
    const int mb = (w >> 1) * 64, nb = (w & 1) * 64;
    const int mrow = l & 15, colq = (l >> 4) * 8;
    fv4 acc[4][4] = {};
    for (int k0 = 0; k0 < K; k0 += 32) {
        gl_lds16(gA0 + k0, &Ash[tid * 8]);
        gl_lds16(gA1 + k0, &Ash[2048 + tid * 8]);
        gl_lds16(gB0 + k0, &Bsh[tid * 8]);
        gl_lds16(gB1 + k0, &Bsh[2048 + tid * 8]);
        __syncthreads();
        f16x8 af[4], bf[4];
#pragma unroll
        for (int i = 0; i < 4; ++i)
            af[i] = *(const f16x8*)&Ash[(mb + i * 16 + mrow) * 32 + colq];
#pragma unroll
        for (int i = 0; i < 4; ++i)
            bf[i] = *(const f16x8*)&Bsh[(nb + i * 16 + mrow) * 32 + colq];
#pragma unroll
        for (int mt = 0; mt < 4; ++mt)
#pragma unroll
            for (int nt = 0; nt < 4; ++nt)
                acc[mt][nt] = __builtin_amdgcn_mfma_f32_16x16x32_f16(
                    af[mt], bf[nt], acc[mt][nt], 0, 0, 0);
        __syncthreads();
    }
    float bv[4];
#pragma unroll
    for (int nt = 0; nt < 4; ++nt) bv[nt] = bias[n0 + nb + nt * 16 + mrow];
    const int rq = (l >> 4) * 4;
#pragma unroll
    for (int mt = 0; mt < 4; ++mt)
#pragma unroll
        for (int nt = 0; nt < 4; ++nt)
#pragma unroll
            for (int i = 0; i < 4; ++i) {
                float v = acc[mt][nt][i] + bv[nt];
                if (act) v = fmaxf(v, 0.f);
                C[(m0 + mb + mt * 16 + rq + i) * (long)N + (n0 + nb + nt * 16 + mrow)] = f2us(v);
            }
}

// ---------------- GI GEMM (N=768, K=256): stores into gru-packed layout -------
// GIp[((((t*16+blk)*8 + w)*64 + lane)*24 + u*4 + i] ; u = gate*2 + s
__global__ __launch_bounds__(256) void gemm_gi(
    const u16* __restrict__ A, const u16* __restrict__ B,
    const float* __restrict__ bias, u16* __restrict__ GIp)
{
    __shared__ u16 Ash[4096] __attribute__((aligned(16)));
    __shared__ u16 Bsh[4096] __attribute__((aligned(16)));
    const int tid = threadIdx.x;
    const int l = tid & 63, w = tid >> 6;
    const long m0 = (long)blockIdx.y * 128;
    const int n0 = blockIdx.x * 128;
    const int r = tid >> 2, c8 = (tid & 3) * 8;
    const u16* gA0 = A + (m0 + r) * 256 + c8;
    const u16* gA1 = A + (m0 + 64 + r) * 256 + c8;
    const u16* gB0 = B + (long)(n0 + r) * 256 + c8;
    const u16* gB1 = B + (long)(n0 + 64 + r) * 256 + c8;
    const int mb = (w >> 1) * 64, nb = (w & 1) * 64;
    const int mrow = l & 15, colq = (l >> 4) * 8;
    fv4 acc[4][4] = {};
    for (int k0 = 0; k0 < 256; k0 += 32) {
        gl_lds16(gA0 + k0, &Ash[tid * 8]);
        gl_lds16(gA1 + k0, &Ash[2048 + tid * 8]);
        gl_lds16(gB0 + k0, &Bsh[tid * 8]);
        gl_lds16(gB1 + k0, &Bsh[2048 + tid * 8]);
        __syncthreads();
        f16x8 af[4], bf[4];
#pragma unroll
        for (int i = 0; i < 4; ++i)
            af[i] = *(const f16x8*)&Ash[(mb + i * 16 + mrow) * 32 + colq];
#pragma unroll
        for (int i = 0; i < 4; ++i)
            bf[i] = *(const f16x8*)&Bsh[(nb + i * 16 + mrow) * 32 + colq];
#pragma unroll
        for (int mt = 0; mt < 4; ++mt)
#pragma unroll
            for (int nt = 0; nt < 4; ++nt)
                acc[mt][nt] = __builtin_amdgcn_mfma_f32_16x16x32_f16(
                    af[mt], bf[nt], acc[mt][nt], 0, 0, 0);
        __syncthreads();
    }
    float bv[4];
#pragma unroll
    for (int nt = 0; nt < 4; ++nt) bv[nt] = bias[n0 + nb + nt * 16 + mrow];
    const int rq = (l >> 4) * 4;
#pragma unroll
    for (int mt = 0; mt < 4; ++mt)
#pragma unroll
        for (int nt = 0; nt < 4; ++nt)
#pragma unroll
            for (int i = 0; i < 4; ++i) {
                float v = acc[mt][nt][i] + bv[nt];
                int m = (int)(m0 + mb + mt * 16 + rq + i);
                int n = n0 + nb + nt * 16 + mrow;
                int t  = m >> 8, b = m & 255;
                int blk = b >> 4, rb = b & 15, q = rb >> 2, i2 = rb & 3;
                int g = n >> 8, c = n & 255, w2 = c >> 5, s = (c >> 4) & 1, cl = c & 15;
                size_t idx = ((((size_t)t * 16 + blk) * 8 + w2) * 64 + (q * 16 + cl)) * 24
                             + (g * 2 + s) * 4 + i2;
                GIp[idx] = f2us(v);
            }
}

// ---------------- sequential GRU v2: W_hh in regs (kt 0-5) + LDS (kt 6-7) ----
// 16 blocks x 512 threads. Block owns batch rows [16g,16g+16), wave w owns
// j-tiles jt = gate*16 + 2w + s. Zero global W traffic in the t-loop.
__global__ __launch_bounds__(512) void gru_seq2(
    const u16* __restrict__ Wp, const u16* __restrict__ GIp,
    const float* __restrict__ bhh, u16* __restrict__ Hout)
{
    __shared__ u16 h_sh[4096] __attribute__((aligned(16)));    // h in A-frag layout
    __shared__ u16 Wl[49152] __attribute__((aligned(16)));     // kt 6,7: [2][48][64][8]
    const int tid = threadIdx.x;
    const int l = tid & 63, w = tid >> 6;
    const int blk = blockIdx.x;
    const int bg = blk * 16;
    const int col = l & 15, quad = l >> 4;

    for (int i = tid; i < 4096; i += 512) h_sh[i] = 0;
#pragma unroll
    for (int kk = 0; kk < 2; ++kk)
        for (int idx = tid; idx < 3072; idx += 512)
            *(f16x8*)&Wl[(size_t)(kk * 3072 + idx) * 8] =
                *(const f16x8*)&Wp[(((size_t)(idx >> 6) * 8 + 6 + kk) * 64 + (idx & 63)) * 8];

    int jts[6];
#pragma unroll
    for (int g = 0; g < 3; ++g)
#pragma unroll
        for (int s = 0; s < 2; ++s) jts[g * 2 + s] = g * 16 + 2 * w + s;

    // W_hh fragments kt 0..5 in registers: 36 f16x8 = 144 VGPRs
    f16x8 wf[6][6];
#pragma unroll
    for (int u = 0; u < 6; ++u)
#pragma unroll
        for (int kt = 0; kt < 6; ++kt)
            wf[u][kt] = *(const f16x8*)&Wp[(((size_t)jts[u] * 8 + kt) * 64 + l) * 8];

    float hbn[2] = { bhh[512 + 32 * w + col], bhh[512 + 32 * w + 16 + col] };

    const u16* gbase = GIp + ((size_t)(blk * 8 + w) * 64 + l) * 24;
    f16x8 gcur[3], gnxt[3];
#pragma unroll
    for (int j = 0; j < 3; ++j) gcur[j] = *(const f16x8*)(gbase + j * 8);

    float hold[2][4] = {};
    u16* hout_base = Hout + ((size_t)(bg + quad * 4) * 256) + 32 * w + col;
    __syncthreads();

    for (int t = 0; t < TT; ++t) {
        // prefetch next step's gi (full step of latency cover)
        const u16* gn = gbase + (size_t)(t < TT - 1 ? t + 1 : t) * 196608;
#pragma unroll
        for (int j = 0; j < 3; ++j) gnxt[j] = *(const f16x8*)(gn + j * 8);

        fv4 acc[6] = {};
#pragma unroll
        for (int kt = 0; kt < 6; ++kt) {
            f16x8 a = *(const f16x8*)&h_sh[(kt * 64 + l) * 8];
#pragma unroll
            for (int u = 0; u < 6; ++u)
                acc[u] = __builtin_amdgcn_mfma_f32_16x16x32_f16(a, wf[u][kt], acc[u], 0, 0, 0);
        }
#pragma unroll
        for (int kk = 0; kk < 2; ++kk) {
            f16x8 a = *(const f16x8*)&h_sh[((6 + kk) * 64 + l) * 8];
#pragma unroll
            for (int u = 0; u < 6; ++u) {
                f16x8 bw = *(const f16x8*)&Wl[(size_t)(kk * 3072 + jts[u] * 64 + l) * 8];
                acc[u] = __builtin_amdgcn_mfma_f32_16x16x32_f16(a, bw, acc[u], 0, 0, 0);
            }
        }
        __syncthreads();   // all h_sh reads done before overwrite
        u16* hp = hout_base + (size_t)t * 65536;
#pragma unroll
        for (int s = 0; s < 2; ++s) {
            const int q2 = s * 2 + (col >> 3);
#pragma unroll
            for (int i = 0; i < 4; ++i) {
                float pr  = (float)gcur[0][s * 4 + i] + acc[0 + s][i];   // biases folded
                float pz  = (float)gcur[1][s * 4 + i] + acc[2 + s][i];
                float h_n = acc[4 + s][i] + hbn[s];
                float rg = 1.f / (1.f + __expf(-pr));
                float zg = 1.f / (1.f + __expf(-pz));
                float pre = (float)gcur[2][s * 4 + i] + rg * h_n;
                float ea = __expf(-2.f * fabsf(pre));
                float th = (1.f - ea) / (1.f + ea);
                float ng = (pre >= 0.f) ? th : -th;
                float hn = (1.f - zg) * ng + zg * hold[s][i];
                hold[s][i] = hn;
                u16 hu = f2us(hn);
                h_sh[(w * 64 + q2 * 16 + quad * 4 + i) * 8 + (col & 7)] = hu;
                hp[(size_t)i * 256 + s * 16] = hu;
            }
        }
#pragma unroll
        for (int j = 0; j < 3; ++j) gcur[j] = gnxt[j];
        __syncthreads();
    }
}

// ---------------- head: out[m, 0..17] = Q1[m,:512] @ W2b^T + b2b (fp32 out) ---
__global__ __launch_bounds__(256) void head_gemm(
    const u16* __restrict__ Q1, const u16* __restrict__ W2p,
    const float* __restrict__ b2, float* __restrict__ out)
{
    __shared__ u16 Ash[4096] __attribute__((aligned(16)));
    __shared__ u16 Bsh[16384] __attribute__((aligned(16)));
    const int tid = threadIdx.x;
    const int l = tid & 63, w = tid >> 6;
    const long m0 = (long)blockIdx.x * 128;
    const int col = l & 15, quad = l >> 4, colq = quad * 8;
    for (int i = tid * 8; i < 16384; i += 2048)
        *(f16x8*)&Bsh[i] = *(const f16x8*)&W2p[i];
    const int r = tid >> 2, c8 = (tid & 3) * 8;
    const u16* gA0 = Q1 + (m0 + r) * 512 + c8;
    const u16* gA1 = Q1 + (m0 + 64 + r) * 512 + c8;
    fv4 acc[2][2] = {};
    for (int k0 = 0; k0 < 512; k0 += 32) {
        gl_lds16(gA0 + k0, &Ash[tid * 8]);
        gl_lds16(gA1 + k0, &Ash[2048 + tid * 8]);
        __syncthreads();
        const int kt = k0 >> 5;
        f16x8 af[2], bf[2];
#pragma unroll
        for (int mt = 0; mt < 2; ++mt)
            af[mt] = *(const f16x8*)&Ash[(w * 32 + mt * 16 + col) * 32 + colq];
#pragma unroll
        for (int nt = 0; nt < 2; ++nt)
            bf[nt] = *(const f16x8*)&Bsh[((nt * 16 + kt) * 64 + l) * 8];
#pragma unroll
        for (int mt = 0; mt < 2; ++mt)
#pragma unroll
            for (int nt = 0; nt < 2; ++nt)
                acc[mt][nt] = __builtin_amdgcn_mfma_f32_16x16x32_f16(
                    af[mt], bf[nt], acc[mt][nt], 0, 0, 0);
        __syncthreads();
    }
    const int rq = quad * 4;
#pragma unroll
    for (int nt = 0; nt < 2; ++nt) {
        int c = nt * 16 + col;
        if (c < 18) {
            float bias = b2[c];
#pragma unroll
            for (int mt = 0; mt < 2; ++mt)
#pragma unroll
                for (int i = 0; i < 4; ++i)
                    out[(m0 + w * 32 + mt * 16 + rq + i) * 18 + c] = acc[mt][nt][i] + bias;
        }
    }
}

extern "C" void kernel_launch(void* const* d_in, const int* in_sizes, int n_in,
                              void* d_out, int out_size, void* d_ws, size_t ws_size,
                              hipStream_t stream) {
    const float* x   = (const float*)d_in[0];
    const float* W1a = (const float*)d_in[1];
    const float* b1a = (const float*)d_in[2];
    const float* W1b = (const float*)d_in[3];
    const float* b1b = (const float*)d_in[4];
    const float* Wih = (const float*)d_in[5];
    const float* bih = (const float*)d_in[6];
    const float* Whh = (const float*)d_in[7];
    const float* bhh = (const float*)d_in[8];
    const float* W2a = (const float*)d_in[9];
    const float* b2a = (const float*)d_in[10];
    const float* W2b = (const float*)d_in[11];
    const float* b2b = (const float*)d_in[12];

    char* ws = (char*)d_ws;
    u16* R    = (u16*)ws;                 // A1 [131072,512]f16, then GIp packed
    u16* A2b  = (u16*)(ws + 201326592);   // 67108864 B
    u16* XH   = (u16*)(ws + 268435456);   // 67108864 B (x fp16, later Hout)
    // bsum lives in the tail of XH: x-f16 there is dead after gemm1, and gru
    // overwrites it (as Hout) only after gemm_gi has consumed bsum.
    float* bsum = (float*)(ws + 268435456 + 67108864 - 4096);
    u16* W1ah = (u16*)(ws + 335544320);   //   262144 B
    u16* W1bh = (u16*)(ws + 335806464);   //   262144 B
    u16* Wihh = (u16*)(ws + 336068608);   //   393216 B
    u16* W2ah = (u16*)(ws + 336461824);   //   262144 B
    u16* Wpk  = (u16*)(ws + 336723968);   //   393216 B
    u16* W2p  = (u16*)(ws + 337117184);   //    32768 B
    if (ws_size < 337149952) {
        fprintf(stderr, "kernel_launch: ws too small (%zu < 337149952)\n", ws_size);
    }

    cvt_f32_f16<<<dim3(2048), dim3(256), 0, stream>>>(x, XH, 33554432);
    cvt_f32_f16<<<dim3(64), dim3(256), 0, stream>>>(W1a, W1ah, 131072);
    cvt_f32_f16<<<dim3(64), dim3(256), 0, stream>>>(W1b, W1bh, 131072);
    cvt_f32_f16<<<dim3(96), dim3(256), 0, stream>>>(Wih, Wihh, 196608);
    cvt_f32_f16<<<dim3(64), dim3(256), 0, stream>>>(W2a, W2ah, 131072);
    pack_whh<<<dim3(96), dim3(256), 0, stream>>>(Whh, Wpk);
    pack_w2b<<<dim3(8), dim3(256), 0, stream>>>(W2b, W2p);

    // Phase A
    gemm_bt<<<dim3(4, 1024), dim3(256), 0, stream>>>(XH, W1ah, b1a, R,   512, 256, 1);
    bias_fold<<<dim3(3), dim3(256), 0, stream>>>(bih, bhh, bsum);   // after gemm1 read XH
    gemm_bt<<<dim3(2, 1024), dim3(256), 0, stream>>>(R,  W1bh, b1b, A2b, 256, 512, 1);
    gemm_gi<<<dim3(6, 1024), dim3(256), 0, stream>>>(A2b, Wihh, bsum, R);
    // Phase R: sequential GRU
    gru_seq2<<<dim3(16), dim3(512), 0, stream>>>(Wpk, R, bhh, XH);
    // Phase B
    gemm_bt<<<dim3(4, 1024), dim3(256), 0, stream>>>(XH, W2ah, b2a, R, 512, 256, 1);
    head_gemm<<<dim3(1024), dim3(256), 0, stream>>>(R, W2p, b2b, (float*)d_out);
}

// Round 5
// 1466.350 us; speedup vs baseline: 2.2293x; 1.3584x over previous
//
#include <hip/hip_runtime.h>
#include <hip/hip_fp16.h>
#include <cstdio>

typedef unsigned short u16;
typedef __attribute__((ext_vector_type(8))) _Float16 f16x8;
typedef __attribute__((ext_vector_type(4))) float fv4;

#define TT 512
#define BB 256

__device__ __forceinline__ float us2f(u16 u) {
    union { u16 u; _Float16 h; } c; c.u = u; return (float)c.h;
}
__device__ __forceinline__ u16 f2us(float f) {
    union { u16 u; _Float16 h; } c; c.h = (_Float16)f; return c.u;
}

// async global->LDS, 16B per lane. LDS dest must be wave-uniform base + lane*16.
__device__ __forceinline__ void gl_lds16(const u16* g, u16* l) {
    __builtin_amdgcn_global_load_lds(
        (const __attribute__((address_space(1))) void*)g,
        (__attribute__((address_space(3))) void*)l, 16, 0, 0);
}

// ---------------- fp32 -> fp16 convert (n % 8 == 0) ----------------
__global__ void cvt_f32_f16(const float* __restrict__ s, u16* __restrict__ d, int n) {
    long stride = (long)gridDim.x * blockDim.x * 8;
    for (long i = ((long)blockIdx.x * blockDim.x + threadIdx.x) * 8; i < n; i += stride) {
        f16x8 o;
#pragma unroll
        for (int j = 0; j < 8; ++j) o[j] = (_Float16)s[i + j];
        *(f16x8*)(d + i) = o;
    }
}

// ---------------- bias fold: bsum = b_ih + (j<512 ? b_hh : 0) ----------------
__global__ void bias_fold(const float* __restrict__ bih, const float* __restrict__ bhh,
                          float* __restrict__ bsum) {
    int i = blockIdx.x * blockDim.x + threadIdx.x;
    if (i < 768) bsum[i] = bih[i] + (i < 512 ? bhh[i] : 0.f);
}

// ---------------- pack W_hh [768,256] into MFMA B-frag order ----------------
// Wp[((jt*8 + kt)*64 + lane)*8 + i] = Whh[jt*16 + (lane&15)][kt*32 + (lane>>4)*8 + i]
__global__ void pack_whh(const float* __restrict__ W, u16* __restrict__ Wp) {
    int t = blockIdx.x * blockDim.x + threadIdx.x;   // 0..24575
    int l = t & 63;
    int kt = (t >> 6) & 7;
    int jt = t >> 9;                                  // 0..47
    int j = jt * 16 + (l & 15);
    int k = kt * 32 + (l >> 4) * 8;
    f16x8 o;
#pragma unroll
    for (int i = 0; i < 8; ++i) o[i] = (_Float16)W[j * 256 + k + i];
    *(f16x8*)(Wp + (size_t)t * 8) = o;
}

// ---------------- pack W2b [18,512] zero-padded to [32,512] in B-frag order --
__global__ void pack_w2b(const float* __restrict__ W, u16* __restrict__ Wp) {
    int t = blockIdx.x * blockDim.x + threadIdx.x;   // 0..2047
    int l = t & 63;
    int kt = (t >> 6) & 15;
    int nt = t >> 10;                                 // 0..1
    int n = nt * 16 + (l & 15);
    int k = kt * 32 + (l >> 4) * 8;
    f16x8 o;
#pragma unroll
    for (int i = 0; i < 8; ++i)
        o[i] = (n < 18) ? (_Float16)W[n * 512 + k + i] : (_Float16)0.f;
    *(f16x8*)(Wp + (size_t)t * 8) = o;
}

// ---------------- generic fp16 GEMM: C[m,n] = act(sum_k A[m,k]*B[n,k] + bias[n])
__global__ __launch_bounds__(256) void gemm_bt(
    const u16* __restrict__ A, const u16* __restrict__ B,
    const float* __restrict__ bias, u16* __restrict__ C,
    int N, int K, int act)
{
    __shared__ u16 Ash[4096] __attribute__((aligned(16)));
    __shared__ u16 Bsh[4096] __attribute__((aligned(16)));
    const int tid = threadIdx.x;
    const int l = tid & 63, w = tid >> 6;
    const long m0 = (long)blockIdx.y * 128;
    const int n0 = blockIdx.x * 128;
    const int r = tid >> 2, c8 = (tid & 3) * 8;
    const u16* gA0 = A + (m0 + r) * K + c8;
    const u16* gA1 = A + (m0 + 64 + r) * K + c8;
    const u16* gB0 = B + (long)(n0 + r) * K + c8;
    const u16* gB1 = B + (long)(n0 + 64 + r) * K + c8;
    const int mb = (w >> 1) * 64, nb = (w & 1) * 64;
    const int mrow = l & 15, colq = (l >> 4) * 8;
    fv4 acc[4][4] = {};
    for (int k0 = 0; k0 < K; k0 += 32) {
        gl_lds16(gA0 + k0, &Ash[tid * 8]);
        gl_lds16(gA1 + k0, &Ash[2048 + tid * 8]);
        gl_lds16(gB0 + k0, &Bsh[tid * 8]);
        gl_lds16(gB1 + k0, &Bsh[2048 + tid * 8]);
        __syncthreads();
        f16x8 af[4], bf[4];
#pragma unroll
        for (int i = 0; i < 4; ++i)
            af[i] = *(const f16x8*)&Ash[(mb + i * 16 + mrow) * 32 + colq];
#pragma unroll
        for (int i = 0; i < 4; ++i)
            bf[i] = *(const f16x8*)&Bsh[(nb + i * 16 + mrow) * 32 + colq];
#pragma unroll
        for (int mt = 0; mt < 4; ++mt)
#pragma unroll
            for (int nt = 0; nt < 4; ++nt)
                acc[mt][nt] = __builtin_amdgcn_mfma_f32_16x16x32_f16(
                    af[mt], bf[nt], acc[mt][nt], 0, 0, 0);
        __syncthreads();
    }
    float bv[4];
#pragma unroll
    for (int nt = 0; nt < 4; ++nt) bv[nt] = bias[n0 + nb + nt * 16 + mrow];
    const int rq = (l >> 4) * 4;
#pragma unroll
    for (int mt = 0; mt < 4; ++mt)
#pragma unroll
        for (int nt = 0; nt < 4; ++nt)
#pragma unroll
            for (int i = 0; i < 4; ++i) {
                float v = acc[mt][nt][i] + bv[nt];
                if (act) v = fmaxf(v, 0.f);
                C[(m0 + mb + mt * 16 + rq + i) * (long)N + (n0 + nb + nt * 16 + mrow)] = f2us(v);
            }
}

// ---------------- GI GEMM (N=768, K=256): stores into gru-packed layout -------
// GIp[((((t*16+blk)*8 + w)*64 + lane)*24 + u*4 + i] ; u = gate*2 + s
__global__ __launch_bounds__(256) void gemm_gi(
    const u16* __restrict__ A, const u16* __restrict__ B,
    const float* __restrict__ bias, u16* __restrict__ GIp)
{
    __shared__ u16 Ash[4096] __attribute__((aligned(16)));
    __shared__ u16 Bsh[4096] __attribute__((aligned(16)));
    const int tid = threadIdx.x;
    const int l = tid & 63, w = tid >> 6;
    const long m0 = (long)blockIdx.y * 128;
    const int n0 = blockIdx.x * 128;
    const int r = tid >> 2, c8 = (tid & 3) * 8;
    const u16* gA0 = A + (m0 + r) * 256 + c8;
    const u16* gA1 = A + (m0 + 64 + r) * 256 + c8;
    const u16* gB0 = B + (long)(n0 + r) * 256 + c8;
    const u16* gB1 = B + (long)(n0 + 64 + r) * 256 + c8;
    const int mb = (w >> 1) * 64, nb = (w & 1) * 64;
    const int mrow = l & 15, colq = (l >> 4) * 8;
    fv4 acc[4][4] = {};
    for (int k0 = 0; k0 < 256; k0 += 32) {
        gl_lds16(gA0 + k0, &Ash[tid * 8]);
        gl_lds16(gA1 + k0, &Ash[2048 + tid * 8]);
        gl_lds16(gB0 + k0, &Bsh[tid * 8]);
        gl_lds16(gB1 + k0, &Bsh[2048 + tid * 8]);
        __syncthreads();
        f16x8 af[4], bf[4];
#pragma unroll
        for (int i = 0; i < 4; ++i)
            af[i] = *(const f16x8*)&Ash[(mb + i * 16 + mrow) * 32 + colq];
#pragma unroll
        for (int i = 0; i < 4; ++i)
            bf[i] = *(const f16x8*)&Bsh[(nb + i * 16 + mrow) * 32 + colq];
#pragma unroll
        for (int mt = 0; mt < 4; ++mt)
#pragma unroll
            for (int nt = 0; nt < 4; ++nt)
                acc[mt][nt] = __builtin_amdgcn_mfma_f32_16x16x32_f16(
                    af[mt], bf[nt], acc[mt][nt], 0, 0, 0);
        __syncthreads();
    }
    float bv[4];
#pragma unroll
    for (int nt = 0; nt < 4; ++nt) bv[nt] = bias[n0 + nb + nt * 16 + mrow];
    const int rq = (l >> 4) * 4;
#pragma unroll
    for (int mt = 0; mt < 4; ++mt)
#pragma unroll
        for (int nt = 0; nt < 4; ++nt)
#pragma unroll
            for (int i = 0; i < 4; ++i) {
                float v = acc[mt][nt][i] + bv[nt];
                int m = (int)(m0 + mb + mt * 16 + rq + i);
                int n = n0 + nb + nt * 16 + mrow;
                int t  = m >> 8, b = m & 255;
                int blk = b >> 4, rb = b & 15, q = rb >> 2, i2 = rb & 3;
                int g = n >> 8, c = n & 255, w2 = c >> 5, s = (c >> 4) & 1, cl = c & 15;
                size_t idx = ((((size_t)t * 16 + blk) * 8 + w2) * 64 + (q * 16 + cl)) * 24
                             + (g * 2 + s) * 4 + i2;
                GIp[idx] = f2us(v);
            }
}

// ---------------- sequential GRU v4: W_hh hoisted to regs (kt 0-6) + LDS (7) --
// No asm pins (round-3 suspect). __launch_bounds__(512,2) raises the VGPR cap
// to 256 so LLVM can hoist the 42 loop-invariant W-fragment loads (168 VGPRs)
// out of the t-loop naturally. Verification: VGPR_Count must be ~230+.
__global__ __launch_bounds__(512, 2) void gru_seq4(
    const u16* __restrict__ Wp, const u16* __restrict__ GIp,
    const float* __restrict__ bhh, u16* __restrict__ Hout)
{
    __shared__ u16 h_sh[2][4096] __attribute__((aligned(16)));  // dbuf h (A-frag layout)
    __shared__ u16 Wl[24576] __attribute__((aligned(16)));      // kt 7: [48][64][8]
    const int tid = threadIdx.x;
    const int l = tid & 63, w = tid >> 6;
    const int blk = blockIdx.x;
    const int bg = blk * 16;
    const int col = l & 15, quad = l >> 4;

    for (int i = tid; i < 4096; i += 512) h_sh[0][i] = 0;
    for (int idx = tid; idx < 3072; idx += 512)
        *(f16x8*)&Wl[(size_t)idx * 8] =
            *(const f16x8*)&Wp[(((size_t)(idx >> 6) * 8 + 7) * 64 + (idx & 63)) * 8];

    int jts[6];
#pragma unroll
    for (int g = 0; g < 3; ++g)
#pragma unroll
        for (int s = 0; s < 2; ++s) jts[g * 2 + s] = g * 16 + 2 * w + s;

    // W_hh fragments kt 0..6: 42 f16x8 = 168 VGPRs, loop-invariant -> hoisted
    f16x8 wf[6][7];
#pragma unroll
    for (int u = 0; u < 6; ++u)
#pragma unroll
        for (int kt = 0; kt < 7; ++kt)
            wf[u][kt] = *(const f16x8*)&Wp[(((size_t)jts[u] * 8 + kt) * 64 + l) * 8];

    float hbn[2] = { bhh[512 + 32 * w + col], bhh[512 + 32 * w + 16 + col] };

    const u16* gbase = GIp + ((size_t)(blk * 8 + w) * 64 + l) * 24;
    f16x8 gcur[3], gnxt[3];
#pragma unroll
    for (int j = 0; j < 3; ++j) gcur[j] = *(const f16x8*)(gbase + j * 8);

    float hold[2][4] = {};
    u16* hout_base = Hout + ((size_t)(bg + quad * 4) * 256) + 32 * w + col;
    __syncthreads();

    for (int t = 0; t < TT; ++t) {
        const int rd = t & 1, wr = (t + 1) & 1;
        // prefetch next step's gi (full step of latency cover)
        const u16* gn = gbase + (size_t)(t < TT - 1 ? t + 1 : t) * 196608;
#pragma unroll
        for (int j = 0; j < 3; ++j) gnxt[j] = *(const f16x8*)(gn + j * 8);

        fv4 acc[6] = {};
#pragma unroll
        for (int kt = 0; kt < 7; ++kt) {
            f16x8 a = *(const f16x8*)&h_sh[rd][(kt * 64 + l) * 8];
#pragma unroll
            for (int u = 0; u < 6; ++u)
                acc[u] = __builtin_amdgcn_mfma_f32_16x16x32_f16(a, wf[u][kt], acc[u], 0, 0, 0);
        }
        {
            f16x8 a = *(const f16x8*)&h_sh[rd][(7 * 64 + l) * 8];
#pragma unroll
            for (int u = 0; u < 6; ++u) {
                f16x8 bw = *(const f16x8*)&Wl[(size_t)(jts[u] * 64 + l) * 8];
                acc[u] = __builtin_amdgcn_mfma_f32_16x16x32_f16(a, bw, acc[u], 0, 0, 0);
            }
        }
        // epilogue: gates + h update (writes OTHER h buffer -> one barrier/step)
        u16* hp = hout_base + (size_t)t * 65536;
#pragma unroll
        for (int s = 0; s < 2; ++s) {
            const int q2 = s * 2 + (col >> 3);
#pragma unroll
            for (int i = 0; i < 4; ++i) {
                float pr  = (float)gcur[0][s * 4 + i] + acc[0 + s][i];   // biases folded
                float pz  = (float)gcur[1][s * 4 + i] + acc[2 + s][i];
                float h_n = acc[4 + s][i] + hbn[s];
                float rg = __builtin_amdgcn_rcpf(1.f + __expf(-pr));
                float zg = __builtin_amdgcn_rcpf(1.f + __expf(-pz));
                float pre = (float)gcur[2][s * 4 + i] + rg * h_n;
                float ea = __expf(-2.f * fabsf(pre));
                float th = (1.f - ea) * __builtin_amdgcn_rcpf(1.f + ea);
                float ng = (pre >= 0.f) ? th : -th;
                float hn = (1.f - zg) * ng + zg * hold[s][i];
                hold[s][i] = hn;
                u16 hu = f2us(hn);
                h_sh[wr][(w * 64 + q2 * 16 + quad * 4 + i) * 8 + (col & 7)] = hu;
                hp[(size_t)i * 256 + s * 16] = hu;
            }
        }
#pragma unroll
        for (int j = 0; j < 3; ++j) gcur[j] = gnxt[j];
        __syncthreads();
    }
}

// ---------------- head: out[m, 0..17] = Q1[m,:512] @ W2b^T + b2b (fp32 out) ---
__global__ __launch_bounds__(256) void head_gemm(
    const u16* __restrict__ Q1, const u16* __restrict__ W2p,
    const float* __restrict__ b2, float* __restrict__ out)
{
    __shared__ u16 Ash[4096] __attribute__((aligned(16)));
    __shared__ u16 Bsh[16384] __attribute__((aligned(16)));
    const int tid = threadIdx.x;
    const int l = tid & 63, w = tid >> 6;
    const long m0 = (long)blockIdx.x * 128;
    const int col = l & 15, quad = l >> 4, colq = quad * 8;
    for (int i = tid * 8; i < 16384; i += 2048)
        *(f16x8*)&Bsh[i] = *(const f16x8*)&W2p[i];
    const int r = tid >> 2, c8 = (tid & 3) * 8;
    const u16* gA0 = Q1 + (m0 + r) * 512 + c8;
    const u16* gA1 = Q1 + (m0 + 64 + r) * 512 + c8;
    fv4 acc[2][2] = {};
    for (int k0 = 0; k0 < 512; k0 += 32) {
        gl_lds16(gA0 + k0, &Ash[tid * 8]);
        gl_lds16(gA1 + k0, &Ash[2048 + tid * 8]);
        __syncthreads();
        const int kt = k0 >> 5;
        f16x8 af[2], bf[2];
#pragma unroll
        for (int mt = 0; mt < 2; ++mt)
            af[mt] = *(const f16x8*)&Ash[(w * 32 + mt * 16 + col) * 32 + colq];
#pragma unroll
        for (int nt = 0; nt < 2; ++nt)
            bf[nt] = *(const f16x8*)&Bsh[((nt * 16 + kt) * 64 + l) * 8];
#pragma unroll
        for (int mt = 0; mt < 2; ++mt)
#pragma unroll
            for (int nt = 0; nt < 2; ++nt)
                acc[mt][nt] = __builtin_amdgcn_mfma_f32_16x16x32_f16(
                    af[mt], bf[nt], acc[mt][nt], 0, 0, 0);
        __syncthreads();
    }
    const int rq = quad * 4;
#pragma unroll
    for (int nt = 0; nt < 2; ++nt) {
        int c = nt * 16 + col;
        if (c < 18) {
            float bias = b2[c];
#pragma unroll
            for (int mt = 0; mt < 2; ++mt)
#pragma unroll
                for (int i = 0; i < 4; ++i)
                    out[(m0 + w * 32 + mt * 16 + rq + i) * 18 + c] = acc[mt][nt][i] + bias;
        }
    }
}

extern "C" void kernel_launch(void* const* d_in, const int* in_sizes, int n_in,
                              void* d_out, int out_size, void* d_ws, size_t ws_size,
                              hipStream_t stream) {
    const float* x   = (const float*)d_in[0];
    const float* W1a = (const float*)d_in[1];
    const float* b1a = (const float*)d_in[2];
    const float* W1b = (const float*)d_in[3];
    const float* b1b = (const float*)d_in[4];
    const float* Wih = (const float*)d_in[5];
    const float* bih = (const float*)d_in[6];
    const float* Whh = (const float*)d_in[7];
    const float* bhh = (const float*)d_in[8];
    const float* W2a = (const float*)d_in[9];
    const float* b2a = (const float*)d_in[10];
    const float* W2b = (const float*)d_in[11];
    const float* b2b = (const float*)d_in[12];

    char* ws = (char*)d_ws;
    u16* R    = (u16*)ws;                 // A1 [131072,512]f16, then GIp packed
    u16* A2b  = (u16*)(ws + 201326592);   // 67108864 B
    u16* XH   = (u16*)(ws + 268435456);   // 67108864 B (x fp16, later Hout)
    float* bsum = (float*)(ws + 268435456 + 67108864 - 4096);
    u16* W1ah = (u16*)(ws + 335544320);   //   262144 B
    u16* W1bh = (u16*)(ws + 335806464);   //   262144 B
    u16* Wihh = (u16*)(ws + 336068608);   //   393216 B
    u16* W2ah = (u16*)(ws + 336461824);   //   262144 B
    u16* Wpk  = (u16*)(ws + 336723968);   //   393216 B
    u16* W2p  = (u16*)(ws + 337117184);   //    32768 B
    if (ws_size < 337149952) {
        fprintf(stderr, "kernel_launch: ws too small (%zu < 337149952)\n", ws_size);
    }

    cvt_f32_f16<<<dim3(2048), dim3(256), 0, stream>>>(x, XH, 33554432);
    cvt_f32_f16<<<dim3(64), dim3(256), 0, stream>>>(W1a, W1ah, 131072);
    cvt_f32_f16<<<dim3(64), dim3(256), 0, stream>>>(W1b, W1bh, 131072);
    cvt_f32_f16<<<dim3(96), dim3(256), 0, stream>>>(Wih, Wihh, 196608);
    cvt_f32_f16<<<dim3(64), dim3(256), 0, stream>>>(W2a, W2ah, 131072);
    pack_whh<<<dim3(96), dim3(256), 0, stream>>>(Whh, Wpk);
    pack_w2b<<<dim3(8), dim3(256), 0, stream>>>(W2b, W2p);

    // Phase A
    gemm_bt<<<dim3(4, 1024), dim3(256), 0, stream>>>(XH, W1ah, b1a, R,   512, 256, 1);
    bias_fold<<<dim3(3), dim3(256), 0, stream>>>(bih, bhh, bsum);
    gemm_bt<<<dim3(2, 1024), dim3(256), 0, stream>>>(R,  W1bh, b1b, A2b, 256, 512, 1);
    gemm_gi<<<dim3(6, 1024), dim3(256), 0, stream>>>(A2b, Wihh, bsum, R);
    // Phase R: sequential GRU
    gru_seq4<<<dim3(16), dim3(512), 0, stream>>>(Wpk, R, bhh, XH);
    // Phase B
    gemm_bt<<<dim3(4, 1024), dim3(256), 0, stream>>>(XH, W2ah, b2a, R, 512, 256, 1);
    head_gemm<<<dim3(1024), dim3(256), 0, stream>>>(R, W2p, b2b, (float*)d_out);
}